// Round 1
// baseline (764.902 us; speedup 1.0000x reference)
//
#include <hip/hip_runtime.h>

#define N_NODES 100000
#define N_EDGES 800000
// Y layout: [n][kx][ky][o] bf16 (ushort), row = 16 o, plane = 256 per node (512 B)

__device__ __forceinline__ unsigned short f2bf(float f) {
    union { float f; unsigned u; } v; v.f = f;
    unsigned u = v.u;
    return (unsigned short)((u + 0x7FFFu + ((u >> 16) & 1u)) >> 16);  // RNE
}
__device__ __forceinline__ float bflo(unsigned u) {
    union { unsigned u; float f; } v; v.u = u << 16; return v.f;
}
__device__ __forceinline__ float bfhi(unsigned u) {
    union { unsigned u; float f; } v; v.u = u & 0xFFFF0000u; return v.f;
}

// Kernel A: Y[n,k,o] = sum_i x[n,i] * W[k,i,o].  grid.y selects a quad of k;
// k indices are wave-uniform -> W loads are uniform-address (s_load-able, L1-hot).
__global__ __launch_bounds__(256) void y_kernel(
    const float* __restrict__ x, const float* __restrict__ W,
    unsigned short* __restrict__ Y) {
    const int n = blockIdx.x * 256 + threadIdx.x;
    const int kbase = blockIdx.y * 4;
    if (n >= N_NODES) return;

    const float4* xv = (const float4*)(x + n * 16);
    float4 a = xv[0], b = xv[1], c = xv[2], d = xv[3];
    float xr[16] = {a.x,a.y,a.z,a.w, b.x,b.y,b.z,b.w,
                    c.x,c.y,c.z,c.w, d.x,d.y,d.z,d.w};

    float acc[4][16];
#pragma unroll
    for (int kk = 0; kk < 4; ++kk)
#pragma unroll
        for (int o = 0; o < 16; ++o) acc[kk][o] = 0.f;

#pragma unroll
    for (int i = 0; i < 16; ++i) {
#pragma unroll
        for (int kk = 0; kk < 4; ++kk) {
            const float* wrow = W + ((kbase + kk) * 256 + i * 16);
#pragma unroll
            for (int o = 0; o < 16; ++o)
                acc[kk][o] = fmaf(xr[i], wrow[o], acc[kk][o]);
        }
    }

    // pack to bf16, store 4 rows of 32B (contiguous 128B per thread)
    unsigned short* dst = Y + (size_t)n * 256 + kbase * 16;
#pragma unroll
    for (int kk = 0; kk < 4; ++kk) {
        unsigned pk[8];
#pragma unroll
        for (int q = 0; q < 8; ++q)
            pk[q] = (unsigned)f2bf(acc[kk][2*q]) | ((unsigned)f2bf(acc[kk][2*q+1]) << 16);
        uint4* p = (uint4*)(dst + kk * 16);
        p[0] = make_uint4(pk[0], pk[1], pk[2], pk[3]);
        p[1] = make_uint4(pk[4], pk[5], pk[6], pk[7]);
    }
}

// Kernel B: per edge, bilinear basis weights over the 4x4 cell grid, gather the
// 2x2 active (kx,ky) rows of Y[j], combine, atomic-scatter to out[i].
__global__ __launch_bounds__(256) void edge_kernel(
    const float* __restrict__ edge_attr, const int* __restrict__ ei,
    const int* __restrict__ ej, const unsigned short* __restrict__ Y,
    float* __restrict__ out) {
    const int e = blockIdx.x * 256 + threadIdx.x;
    if (e >= N_EDGES) return;
    const int di = ei[e];
    const int sj = ej[e];
    const float2 ea = ((const float2*)edge_attr)[e];
    if (di == sj) return;  // centerIgnore mask

    float ux = fminf(fmaxf(ea.x, -1.f), 1.f);
    float uy = fminf(fmaxf(ea.y, -1.f), 1.f);
    float tx = (ux + 1.f) * 1.5f;     // cell coord in [0,3]
    float ty = (uy + 1.f) * 1.5f;
    int kx0 = min((int)tx, 2);
    int ky0 = min((int)ty, 2);
    float fx = tx - (float)kx0;
    float fy = ty - (float)ky0;
    const float S = 1.f / 128.f;      // OUTPUT_SCALING folded into weights
    float w00 = (1.f - fx) * (1.f - fy) * S;
    float w01 = (1.f - fx) * fy * S;
    float w10 = fx * (1.f - fy) * S;
    float w11 = fx * fy * S;

    // chunk for kx: rows [ky0, ky0+1] = 32 ushorts = 64B contiguous
    const unsigned short* base = Y + (size_t)sj * 256 + (kx0 * 4 + ky0) * 16;
    const uint4* pA = (const uint4*)base;         // kx0
    const uint4* pB = (const uint4*)(base + 64);  // kx0+1
    uint4 a0 = pA[0], a1 = pA[1], a2 = pA[2], a3 = pA[3];
    uint4 b0 = pB[0], b1 = pB[1], b2 = pB[2], b3 = pB[3];

    unsigned ra0[8] = {a0.x,a0.y,a0.z,a0.w, a1.x,a1.y,a1.z,a1.w};  // row (kx0,ky0)
    unsigned ra1[8] = {a2.x,a2.y,a2.z,a2.w, a3.x,a3.y,a3.z,a3.w};  // row (kx0,ky0+1)
    unsigned rb0[8] = {b0.x,b0.y,b0.z,b0.w, b1.x,b1.y,b1.z,b1.w};  // row (kx0+1,ky0)
    unsigned rb1[8] = {b2.x,b2.y,b2.z,b2.w, b3.x,b3.y,b3.z,b3.w};  // row (kx0+1,ky0+1)

    float* o16 = out + (size_t)di * 16;
#pragma unroll
    for (int q = 0; q < 8; ++q) {
        float m0 = bflo(ra0[q]) * w00 + bflo(ra1[q]) * w01
                 + bflo(rb0[q]) * w10 + bflo(rb1[q]) * w11;
        float m1 = bfhi(ra0[q]) * w00 + bfhi(ra1[q]) * w01
                 + bfhi(rb0[q]) * w10 + bfhi(rb1[q]) * w11;
        atomicAdd(o16 + 2 * q, m0);
        atomicAdd(o16 + 2 * q + 1, m1);
    }
}

// Fallback (only if workspace is too small): per-edge direct compute.
__global__ __launch_bounds__(256) void edge_direct(
    const float* __restrict__ x, const float* __restrict__ edge_attr,
    const float* __restrict__ W, const int* __restrict__ ei,
    const int* __restrict__ ej, float* __restrict__ out) {
    const int e = blockIdx.x * 256 + threadIdx.x;
    if (e >= N_EDGES) return;
    const int di = ei[e];
    const int sj = ej[e];
    const float2 ea = ((const float2*)edge_attr)[e];
    if (di == sj) return;

    float ux = fminf(fmaxf(ea.x, -1.f), 1.f);
    float uy = fminf(fmaxf(ea.y, -1.f), 1.f);
    float tx = (ux + 1.f) * 1.5f, ty = (uy + 1.f) * 1.5f;
    int kx0 = min((int)tx, 2), ky0 = min((int)ty, 2);
    float fx = tx - (float)kx0, fy = ty - (float)ky0;
    const float S = 1.f / 128.f;
    float wgt[4] = {(1.f-fx)*(1.f-fy)*S, (1.f-fx)*fy*S, fx*(1.f-fy)*S, fx*fy*S};
    int kidx[4] = {kx0*4+ky0, kx0*4+ky0+1, (kx0+1)*4+ky0, (kx0+1)*4+ky0+1};

    const float* xj = x + (size_t)sj * 16;
    float xr[16];
#pragma unroll
    for (int i = 0; i < 16; ++i) xr[i] = xj[i];

    float msg[16];
#pragma unroll
    for (int o = 0; o < 16; ++o) msg[o] = 0.f;
#pragma unroll
    for (int p = 0; p < 4; ++p) {
        const float* wk = W + kidx[p] * 256;
#pragma unroll
        for (int i = 0; i < 16; ++i) {
            float xw = xr[i] * wgt[p];
#pragma unroll
            for (int o = 0; o < 16; ++o)
                msg[o] = fmaf(xw, wk[i * 16 + o], msg[o]);
        }
    }
    float* o16 = out + (size_t)di * 16;
#pragma unroll
    for (int o = 0; o < 16; ++o) atomicAdd(o16 + o, msg[o]);
}

extern "C" void kernel_launch(void* const* d_in, const int* in_sizes, int n_in,
                              void* d_out, int out_size, void* d_ws, size_t ws_size,
                              hipStream_t stream) {
    const float* x         = (const float*)d_in[0];
    const float* edge_attr = (const float*)d_in[1];
    const float* W         = (const float*)d_in[2];
    const int*   ei        = (const int*)d_in[3];
    const int*   ej        = (const int*)d_in[4];
    float* out = (float*)d_out;

    hipMemsetAsync(d_out, 0, (size_t)out_size * sizeof(float), stream);

    const size_t yBytes = (size_t)N_NODES * 256 * sizeof(unsigned short);
    if (ws_size >= yBytes) {
        unsigned short* Y = (unsigned short*)d_ws;
        dim3 gA((N_NODES + 255) / 256, 4);
        y_kernel<<<gA, 256, 0, stream>>>(x, W, Y);
        edge_kernel<<<(N_EDGES + 255) / 256, 256, 0, stream>>>(edge_attr, ei, ej, Y, out);
    } else {
        edge_direct<<<(N_EDGES + 255) / 256, 256, 0, stream>>>(x, edge_attr, W, ei, ej, out);
    }
}

// Round 2
// 363.221 us; speedup vs baseline: 2.1059x; 2.1059x over previous
//
#include <hip/hip_runtime.h>

#define N_NODES 100000
#define N_EDGES 800000
// Y layout: [n][kx][ky][o] bf16 (ushort), row = 16 o, plane = 256 per node (512 B)

__device__ __forceinline__ unsigned short f2bf(float f) {
    union { float f; unsigned u; } v; v.f = f;
    unsigned u = v.u;
    return (unsigned short)((u + 0x7FFFu + ((u >> 16) & 1u)) >> 16);  // RNE
}
__device__ __forceinline__ float bflo(unsigned u) {
    union { unsigned u; float f; } v; v.u = u << 16; return v.f;
}
__device__ __forceinline__ float bfhi(unsigned u) {
    union { unsigned u; float f; } v; v.u = u & 0xFFFF0000u; return v.f;
}

// ---------------- Kernel A: Y[n,k,o] = sum_i x[n,i] * W[k,i,o] ----------------
__global__ __launch_bounds__(256) void y_kernel(
    const float* __restrict__ x, const float* __restrict__ W,
    unsigned short* __restrict__ Y) {
    const int n = blockIdx.x * 256 + threadIdx.x;
    const int kbase = blockIdx.y * 4;
    if (n >= N_NODES) return;

    const float4* xv = (const float4*)(x + n * 16);
    float4 a = xv[0], b = xv[1], c = xv[2], d = xv[3];
    float xr[16] = {a.x,a.y,a.z,a.w, b.x,b.y,b.z,b.w,
                    c.x,c.y,c.z,c.w, d.x,d.y,d.z,d.w};

    float acc[4][16];
#pragma unroll
    for (int kk = 0; kk < 4; ++kk)
#pragma unroll
        for (int o = 0; o < 16; ++o) acc[kk][o] = 0.f;

#pragma unroll
    for (int i = 0; i < 16; ++i) {
#pragma unroll
        for (int kk = 0; kk < 4; ++kk) {
            const float* wrow = W + ((kbase + kk) * 256 + i * 16);
#pragma unroll
            for (int o = 0; o < 16; ++o)
                acc[kk][o] = fmaf(xr[i], wrow[o], acc[kk][o]);
        }
    }

    unsigned short* dst = Y + (size_t)n * 256 + kbase * 16;
#pragma unroll
    for (int kk = 0; kk < 4; ++kk) {
        unsigned pk[8];
#pragma unroll
        for (int q = 0; q < 8; ++q)
            pk[q] = (unsigned)f2bf(acc[kk][2*q]) | ((unsigned)f2bf(acc[kk][2*q+1]) << 16);
        uint4* p = (uint4*)(dst + kk * 16);
        p[0] = make_uint4(pk[0], pk[1], pk[2], pk[3]);
        p[1] = make_uint4(pk[4], pk[5], pk[6], pk[7]);
    }
}

// ---------------- CSR build ----------------
// hist: count edges per destination, record per-edge rank (arrival order).
__global__ __launch_bounds__(256) void hist_kernel(
    const int* __restrict__ ei, const int* __restrict__ ej,
    int* __restrict__ cnt, int* __restrict__ rank) {
    const int e = blockIdx.x * 256 + threadIdx.x;
    if (e >= N_EDGES) return;
    const int di = ei[e];
    if (di == ej[e]) { rank[e] = -1; return; }   // centerIgnore
    rank[e] = atomicAdd(&cnt[di], 1);
}

// scan: single block of 1024; thread t owns a contiguous chunk of ~98 counts.
// Pass 1: local sums -> block exclusive scan (shuffle, 2 barriers).
// Pass 2: write running exclusive prefix.
__global__ __launch_bounds__(1024) void scan_kernel(
    const int* __restrict__ cnt, int* __restrict__ offs) {
    const int tid = threadIdx.x;
    const int CH = (N_NODES + 1023) / 1024;           // 98
    const int lo = tid * CH;
    const int hi = min(lo + CH, N_NODES);

    int sum = 0;
    for (int i = lo; i < hi; ++i) sum += cnt[i];

    // block exclusive scan of `sum` across 1024 threads
    const int lane = tid & 63, wv = tid >> 6;
    int v = sum;
#pragma unroll
    for (int off = 1; off < 64; off <<= 1) {
        int t2 = __shfl_up(v, off);
        if (lane >= off) v += t2;
    }
    __shared__ int wsum[16];
    __shared__ int woff[16];
    if (lane == 63) wsum[wv] = v;
    __syncthreads();
    if (tid < 16) {
        int w = wsum[tid];
        int iw = w;
#pragma unroll
        for (int off = 1; off < 16; off <<= 1) {
            int t2 = __shfl_up(iw, off, 16);
            if (tid >= off) iw += t2;
        }
        woff[tid] = iw - w;   // exclusive
    }
    __syncthreads();
    int base = woff[wv] + (v - sum);   // exclusive prefix for this thread

    int run = base;
    for (int i = lo; i < hi; ++i) {
        offs[i] = run;
        run += cnt[i];
    }
    if (tid == 1023) offs[N_NODES] = run;   // grand total
}

// scatter: atomic-free slot write of per-edge meta (src|cell + bilinear weights)
__global__ __launch_bounds__(256) void scatter_kernel(
    const float* __restrict__ edge_attr, const int* __restrict__ ei,
    const int* __restrict__ ej, const int* __restrict__ offs,
    const int* __restrict__ rank, int* __restrict__ metaM,
    float4* __restrict__ metaW) {
    const int e = blockIdx.x * 256 + threadIdx.x;
    if (e >= N_EDGES) return;
    const int r = rank[e];
    if (r < 0) return;
    const int di = ei[e];
    const int sj = ej[e];
    const float2 ea = ((const float2*)edge_attr)[e];

    float ux = fminf(fmaxf(ea.x, -1.f), 1.f);
    float uy = fminf(fmaxf(ea.y, -1.f), 1.f);
    float tx = (ux + 1.f) * 1.5f;
    float ty = (uy + 1.f) * 1.5f;
    int kx0 = min((int)tx, 2);
    int ky0 = min((int)ty, 2);
    float fx = tx - (float)kx0;
    float fy = ty - (float)ky0;
    const float S = 1.f / 128.f;   // OUTPUT_SCALING folded in
    float w00 = (1.f - fx) * (1.f - fy) * S;
    float w01 = (1.f - fx) * fy * S;
    float w10 = fx * (1.f - fy) * S;
    float w11 = fx * fy * S;

    const int p = offs[di] + r;
    metaM[p] = (sj << 4) | (kx0 * 4 + ky0);
    metaW[p] = make_float4(w00, w01, w10, w11);
}

// gather: one thread per destination node; register accumulator; plain store.
__global__ __launch_bounds__(256) void gather_kernel(
    const int* __restrict__ offs, const int* __restrict__ metaM,
    const float4* __restrict__ metaW, const unsigned short* __restrict__ Y,
    float* __restrict__ out) {
    const int n = blockIdx.x * 256 + threadIdx.x;
    if (n >= N_NODES) return;
    const int s = offs[n];
    const int t = offs[n + 1];

    float acc[16];
#pragma unroll
    for (int o = 0; o < 16; ++o) acc[o] = 0.f;

    for (int p = s; p < t; ++p) {
        const int m = metaM[p];
        const float4 w = metaW[p];
        const unsigned short* base = Y + (size_t)(m >> 4) * 256 + (m & 15) * 16;
        const uint4* pA = (const uint4*)base;          // rows (kx0,ky0),(kx0,ky0+1)
        const uint4* pB = (const uint4*)(base + 64);   // rows (kx0+1,ky0),(kx0+1,ky0+1)
        uint4 a0 = pA[0], a1 = pA[1], a2 = pA[2], a3 = pA[3];
        uint4 b0 = pB[0], b1 = pB[1], b2 = pB[2], b3 = pB[3];

        unsigned ra0[8] = {a0.x,a0.y,a0.z,a0.w, a1.x,a1.y,a1.z,a1.w};
        unsigned ra1[8] = {a2.x,a2.y,a2.z,a2.w, a3.x,a3.y,a3.z,a3.w};
        unsigned rb0[8] = {b0.x,b0.y,b0.z,b0.w, b1.x,b1.y,b1.z,b1.w};
        unsigned rb1[8] = {b2.x,b2.y,b2.z,b2.w, b3.x,b3.y,b3.z,b3.w};

#pragma unroll
        for (int q = 0; q < 8; ++q) {
            acc[2*q]   += bflo(ra0[q]) * w.x + bflo(ra1[q]) * w.y
                        + bflo(rb0[q]) * w.z + bflo(rb1[q]) * w.w;
            acc[2*q+1] += bfhi(ra0[q]) * w.x + bfhi(ra1[q]) * w.y
                        + bfhi(rb0[q]) * w.z + bfhi(rb1[q]) * w.w;
        }
    }

    float4* o4 = (float4*)(out + (size_t)n * 16);
    o4[0] = make_float4(acc[0],  acc[1],  acc[2],  acc[3]);
    o4[1] = make_float4(acc[4],  acc[5],  acc[6],  acc[7]);
    o4[2] = make_float4(acc[8],  acc[9],  acc[10], acc[11]);
    o4[3] = make_float4(acc[12], acc[13], acc[14], acc[15]);
}

// ---------------- fallback: previous atomic-scatter version ----------------
__global__ __launch_bounds__(256) void edge_kernel(
    const float* __restrict__ edge_attr, const int* __restrict__ ei,
    const int* __restrict__ ej, const unsigned short* __restrict__ Y,
    float* __restrict__ out) {
    const int e = blockIdx.x * 256 + threadIdx.x;
    if (e >= N_EDGES) return;
    const int di = ei[e];
    const int sj = ej[e];
    const float2 ea = ((const float2*)edge_attr)[e];
    if (di == sj) return;

    float ux = fminf(fmaxf(ea.x, -1.f), 1.f);
    float uy = fminf(fmaxf(ea.y, -1.f), 1.f);
    float tx = (ux + 1.f) * 1.5f;
    float ty = (uy + 1.f) * 1.5f;
    int kx0 = min((int)tx, 2);
    int ky0 = min((int)ty, 2);
    float fx = tx - (float)kx0;
    float fy = ty - (float)ky0;
    const float S = 1.f / 128.f;
    float w00 = (1.f - fx) * (1.f - fy) * S;
    float w01 = (1.f - fx) * fy * S;
    float w10 = fx * (1.f - fy) * S;
    float w11 = fx * fy * S;

    const unsigned short* base = Y + (size_t)sj * 256 + (kx0 * 4 + ky0) * 16;
    const uint4* pA = (const uint4*)base;
    const uint4* pB = (const uint4*)(base + 64);
    uint4 a0 = pA[0], a1 = pA[1], a2 = pA[2], a3 = pA[3];
    uint4 b0 = pB[0], b1 = pB[1], b2 = pB[2], b3 = pB[3];

    unsigned ra0[8] = {a0.x,a0.y,a0.z,a0.w, a1.x,a1.y,a1.z,a1.w};
    unsigned ra1[8] = {a2.x,a2.y,a2.z,a2.w, a3.x,a3.y,a3.z,a3.w};
    unsigned rb0[8] = {b0.x,b0.y,b0.z,b0.w, b1.x,b1.y,b1.z,b1.w};
    unsigned rb1[8] = {b2.x,b2.y,b2.z,b2.w, b3.x,b3.y,b3.z,b3.w};

    float* o16 = out + (size_t)di * 16;
#pragma unroll
    for (int q = 0; q < 8; ++q) {
        float m0 = bflo(ra0[q]) * w00 + bflo(ra1[q]) * w01
                 + bflo(rb0[q]) * w10 + bflo(rb1[q]) * w11;
        float m1 = bfhi(ra0[q]) * w00 + bfhi(ra1[q]) * w01
                 + bfhi(rb0[q]) * w10 + bfhi(rb1[q]) * w11;
        atomicAdd(o16 + 2 * q, m0);
        atomicAdd(o16 + 2 * q + 1, m1);
    }
}

// last-resort fallback: per-edge direct compute
__global__ __launch_bounds__(256) void edge_direct(
    const float* __restrict__ x, const float* __restrict__ edge_attr,
    const float* __restrict__ W, const int* __restrict__ ei,
    const int* __restrict__ ej, float* __restrict__ out) {
    const int e = blockIdx.x * 256 + threadIdx.x;
    if (e >= N_EDGES) return;
    const int di = ei[e];
    const int sj = ej[e];
    const float2 ea = ((const float2*)edge_attr)[e];
    if (di == sj) return;

    float ux = fminf(fmaxf(ea.x, -1.f), 1.f);
    float uy = fminf(fmaxf(ea.y, -1.f), 1.f);
    float tx = (ux + 1.f) * 1.5f, ty = (uy + 1.f) * 1.5f;
    int kx0 = min((int)tx, 2), ky0 = min((int)ty, 2);
    float fx = tx - (float)kx0, fy = ty - (float)ky0;
    const float S = 1.f / 128.f;
    float wgt[4] = {(1.f-fx)*(1.f-fy)*S, (1.f-fx)*fy*S, fx*(1.f-fy)*S, fx*fy*S};
    int kidx[4] = {kx0*4+ky0, kx0*4+ky0+1, (kx0+1)*4+ky0, (kx0+1)*4+ky0+1};

    const float* xj = x + (size_t)sj * 16;
    float xr[16];
#pragma unroll
    for (int i = 0; i < 16; ++i) xr[i] = xj[i];

    float msg[16];
#pragma unroll
    for (int o = 0; o < 16; ++o) msg[o] = 0.f;
#pragma unroll
    for (int p = 0; p < 4; ++p) {
        const float* wk = W + kidx[p] * 256;
#pragma unroll
        for (int i = 0; i < 16; ++i) {
            float xw = xr[i] * wgt[p];
#pragma unroll
            for (int o = 0; o < 16; ++o)
                msg[o] = fmaf(xw, wk[i * 16 + o], msg[o]);
        }
    }
    float* o16 = out + (size_t)di * 16;
#pragma unroll
    for (int o = 0; o < 16; ++o) atomicAdd(o16 + o, msg[o]);
}

extern "C" void kernel_launch(void* const* d_in, const int* in_sizes, int n_in,
                              void* d_out, int out_size, void* d_ws, size_t ws_size,
                              hipStream_t stream) {
    const float* x         = (const float*)d_in[0];
    const float* edge_attr = (const float*)d_in[1];
    const float* W         = (const float*)d_in[2];
    const int*   ei        = (const int*)d_in[3];
    const int*   ej        = (const int*)d_in[4];
    float* out = (float*)d_out;

    // workspace layout (all 16B aligned)
    const size_t oY     = 0;                               // 51,200,000 B
    const size_t oCnt   = oY + (size_t)N_NODES * 256 * 2;  // 400,000 B
    const size_t oOffs  = oCnt + 400000;                   // 400,016 B (N+1 ints, padded)
    const size_t oRank  = oOffs + 400016;                  // 3,200,000 B
    const size_t oMetaM = oRank + (size_t)N_EDGES * 4;     // 3,200,000 B
    const size_t oMetaW = oMetaM + (size_t)N_EDGES * 4;    // 12,800,000 B
    const size_t total  = oMetaW + (size_t)N_EDGES * 16;

    char* ws = (char*)d_ws;
    const size_t yBytes = (size_t)N_NODES * 256 * 2;

    if (ws_size >= total) {
        unsigned short* Y  = (unsigned short*)(ws + oY);
        int*    cnt   = (int*)(ws + oCnt);
        int*    offs  = (int*)(ws + oOffs);
        int*    rank  = (int*)(ws + oRank);
        int*    metaM = (int*)(ws + oMetaM);
        float4* metaW = (float4*)(ws + oMetaW);

        hipMemsetAsync(cnt, 0, (size_t)N_NODES * 4, stream);
        dim3 gA((N_NODES + 255) / 256, 4);
        y_kernel<<<gA, 256, 0, stream>>>(x, W, Y);
        hist_kernel<<<(N_EDGES + 255) / 256, 256, 0, stream>>>(ei, ej, cnt, rank);
        scan_kernel<<<1, 1024, 0, stream>>>(cnt, offs);
        scatter_kernel<<<(N_EDGES + 255) / 256, 256, 0, stream>>>(
            edge_attr, ei, ej, offs, rank, metaM, metaW);
        gather_kernel<<<(N_NODES + 255) / 256, 256, 0, stream>>>(
            offs, metaM, metaW, Y, out);
    } else if (ws_size >= yBytes) {
        hipMemsetAsync(d_out, 0, (size_t)out_size * sizeof(float), stream);
        unsigned short* Y = (unsigned short*)d_ws;
        dim3 gA((N_NODES + 255) / 256, 4);
        y_kernel<<<gA, 256, 0, stream>>>(x, W, Y);
        edge_kernel<<<(N_EDGES + 255) / 256, 256, 0, stream>>>(edge_attr, ei, ej, Y, out);
    } else {
        hipMemsetAsync(d_out, 0, (size_t)out_size * sizeof(float), stream);
        edge_direct<<<(N_EDGES + 255) / 256, 256, 0, stream>>>(x, edge_attr, W, ei, ej, out);
    }
}

// Round 3
// 214.402 us; speedup vs baseline: 3.5676x; 1.6941x over previous
//
#include <hip/hip_runtime.h>

#define N_NODES 100000
#define N_EDGES 800000
#define SCAN_B 1024
#define SCAN_G ((N_NODES + SCAN_B - 1) / SCAN_B)   // 98 blocks
// Y layout: [n][kx][ky][o] bf16 (ushort), row = 16 o, plane = 256 per node (512 B)

__device__ __forceinline__ unsigned short f2bf(float f) {
    union { float f; unsigned u; } v; v.f = f;
    unsigned u = v.u;
    return (unsigned short)((u + 0x7FFFu + ((u >> 16) & 1u)) >> 16);  // RNE
}
__device__ __forceinline__ float bflo(unsigned u) {
    union { unsigned u; float f; } v; v.u = u << 16; return v.f;
}
__device__ __forceinline__ float bfhi(unsigned u) {
    union { unsigned u; float f; } v; v.u = u & 0xFFFF0000u; return v.f;
}

// ---------------- Kernel A: Y[n,k,o] = sum_i x[n,i] * W[k,i,o] ----------------
__global__ __launch_bounds__(256) void y_kernel(
    const float* __restrict__ x, const float* __restrict__ W,
    unsigned short* __restrict__ Y) {
    const int n = blockIdx.x * 256 + threadIdx.x;
    const int kbase = blockIdx.y * 4;
    if (n >= N_NODES) return;

    const float4* xv = (const float4*)(x + n * 16);
    float4 a = xv[0], b = xv[1], c = xv[2], d = xv[3];
    float xr[16] = {a.x,a.y,a.z,a.w, b.x,b.y,b.z,b.w,
                    c.x,c.y,c.z,c.w, d.x,d.y,d.z,d.w};

    float acc[4][16];
#pragma unroll
    for (int kk = 0; kk < 4; ++kk)
#pragma unroll
        for (int o = 0; o < 16; ++o) acc[kk][o] = 0.f;

#pragma unroll
    for (int i = 0; i < 16; ++i) {
#pragma unroll
        for (int kk = 0; kk < 4; ++kk) {
            const float* wrow = W + ((kbase + kk) * 256 + i * 16);
#pragma unroll
            for (int o = 0; o < 16; ++o)
                acc[kk][o] = fmaf(xr[i], wrow[o], acc[kk][o]);
        }
    }

    unsigned short* dst = Y + (size_t)n * 256 + kbase * 16;
#pragma unroll
    for (int kk = 0; kk < 4; ++kk) {
        unsigned pk[8];
#pragma unroll
        for (int q = 0; q < 8; ++q)
            pk[q] = (unsigned)f2bf(acc[kk][2*q]) | ((unsigned)f2bf(acc[kk][2*q+1]) << 16);
        uint4* p = (uint4*)(dst + kk * 16);
        p[0] = make_uint4(pk[0], pk[1], pk[2], pk[3]);
        p[1] = make_uint4(pk[4], pk[5], pk[6], pk[7]);
    }
}

// ---------------- CSR build ----------------
__global__ __launch_bounds__(256) void hist_kernel(
    const int* __restrict__ ei, const int* __restrict__ ej,
    int* __restrict__ cnt, int* __restrict__ rank) {
    const int e = blockIdx.x * 256 + threadIdx.x;
    if (e >= N_EDGES) return;
    const int di = ei[e];
    if (di == ej[e]) { rank[e] = -1; return; }   // centerIgnore
    rank[e] = atomicAdd(&cnt[di], 1);
}

// phase 1: per-block exclusive scan of 1024 counts; emit block sums.
__global__ __launch_bounds__(1024) void scan1_kernel(
    const int* __restrict__ cnt, int* __restrict__ offs, int* __restrict__ bsum) {
    const int tid = threadIdx.x;
    const int i = blockIdx.x * SCAN_B + tid;
    int v = (i < N_NODES) ? cnt[i] : 0;
    const int lane = tid & 63, wv = tid >> 6;
    int inc = v;
#pragma unroll
    for (int off = 1; off < 64; off <<= 1) {
        int t2 = __shfl_up(inc, off);
        if (lane >= off) inc += t2;
    }
    __shared__ int wsum[16], woff[16];
    if (lane == 63) wsum[wv] = inc;
    __syncthreads();
    if (tid < 16) {
        int w = wsum[tid], iw = w;
#pragma unroll
        for (int off = 1; off < 16; off <<= 1) {
            int t2 = __shfl_up(iw, off, 16);
            if (tid >= off) iw += t2;
        }
        woff[tid] = iw - w;                       // exclusive wave offset
        if (tid == 15) bsum[blockIdx.x] = iw;     // block total
    }
    __syncthreads();
    if (i < N_NODES) offs[i] = woff[wv] + (inc - v);  // block-local exclusive
}

// phase 2: one small block scans the 98 block sums.
__global__ __launch_bounds__(128) void scan2_kernel(
    const int* __restrict__ bsum, int* __restrict__ bexcl, int* __restrict__ offs) {
    const int tid = threadIdx.x;                  // 128 threads = 2 waves
    int v = (tid < SCAN_G) ? bsum[tid] : 0;
    const int lane = tid & 63, wv = tid >> 6;
    int inc = v;
#pragma unroll
    for (int off = 1; off < 64; off <<= 1) {
        int t2 = __shfl_up(inc, off);
        if (lane >= off) inc += t2;
    }
    __shared__ int w0tot;
    if (wv == 0 && lane == 63) w0tot = inc;
    __syncthreads();
    if (wv == 1) inc += w0tot;
    if (tid < SCAN_G) bexcl[tid] = inc - v;
    if (tid == SCAN_G - 1) offs[N_NODES] = inc;   // grand total
}

// phase 3: add block offsets.
__global__ __launch_bounds__(1024) void scan3_kernel(
    int* __restrict__ offs, const int* __restrict__ bexcl) {
    const int i = blockIdx.x * SCAN_B + threadIdx.x;
    if (i < N_NODES) offs[i] += bexcl[blockIdx.x];
}

// scatter: atomic-free slot write of per-edge meta (src|cell + bilinear weights)
__global__ __launch_bounds__(256) void scatter_kernel(
    const float* __restrict__ edge_attr, const int* __restrict__ ei,
    const int* __restrict__ ej, const int* __restrict__ offs,
    const int* __restrict__ rank, int* __restrict__ metaM,
    float4* __restrict__ metaW) {
    const int e = blockIdx.x * 256 + threadIdx.x;
    if (e >= N_EDGES) return;
    const int r = rank[e];
    if (r < 0) return;
    const int di = ei[e];
    const int sj = ej[e];
    const float2 ea = ((const float2*)edge_attr)[e];

    float ux = fminf(fmaxf(ea.x, -1.f), 1.f);
    float uy = fminf(fmaxf(ea.y, -1.f), 1.f);
    float tx = (ux + 1.f) * 1.5f;
    float ty = (uy + 1.f) * 1.5f;
    int kx0 = min((int)tx, 2);
    int ky0 = min((int)ty, 2);
    float fx = tx - (float)kx0;
    float fy = ty - (float)ky0;
    const float S = 1.f / 128.f;   // OUTPUT_SCALING folded in
    float w00 = (1.f - fx) * (1.f - fy) * S;
    float w01 = (1.f - fx) * fy * S;
    float w10 = fx * (1.f - fy) * S;
    float w11 = fx * fy * S;

    const int p = offs[di] + r;
    metaM[p] = (sj << 4) | (kx0 * 4 + ky0);
    metaW[p] = make_float4(w00, w01, w10, w11);
}

// gather: one thread per destination node; register accumulator; plain store.
__global__ __launch_bounds__(256) void gather_kernel(
    const int* __restrict__ offs, const int* __restrict__ metaM,
    const float4* __restrict__ metaW, const unsigned short* __restrict__ Y,
    float* __restrict__ out) {
    const int n = blockIdx.x * 256 + threadIdx.x;
    if (n >= N_NODES) return;
    const int s = offs[n];
    const int t = offs[n + 1];

    float acc[16];
#pragma unroll
    for (int o = 0; o < 16; ++o) acc[o] = 0.f;

    for (int p = s; p < t; ++p) {
        const int m = metaM[p];
        const float4 w = metaW[p];
        const unsigned short* base = Y + (size_t)(m >> 4) * 256 + (m & 15) * 16;
        const uint4* pA = (const uint4*)base;          // rows (kx0,ky0),(kx0,ky0+1)
        const uint4* pB = (const uint4*)(base + 64);   // rows (kx0+1,ky0),(kx0+1,ky0+1)
        uint4 a0 = pA[0], a1 = pA[1], a2 = pA[2], a3 = pA[3];
        uint4 b0 = pB[0], b1 = pB[1], b2 = pB[2], b3 = pB[3];

        unsigned ra0[8] = {a0.x,a0.y,a0.z,a0.w, a1.x,a1.y,a1.z,a1.w};
        unsigned ra1[8] = {a2.x,a2.y,a2.z,a2.w, a3.x,a3.y,a3.z,a3.w};
        unsigned rb0[8] = {b0.x,b0.y,b0.z,b0.w, b1.x,b1.y,b1.z,b1.w};
        unsigned rb1[8] = {b2.x,b2.y,b2.z,b2.w, b3.x,b3.y,b3.z,b3.w};

#pragma unroll
        for (int q = 0; q < 8; ++q) {
            acc[2*q]   += bflo(ra0[q]) * w.x + bflo(ra1[q]) * w.y
                        + bflo(rb0[q]) * w.z + bflo(rb1[q]) * w.w;
            acc[2*q+1] += bfhi(ra0[q]) * w.x + bfhi(ra1[q]) * w.y
                        + bfhi(rb0[q]) * w.z + bfhi(rb1[q]) * w.w;
        }
    }

    float4* o4 = (float4*)(out + (size_t)n * 16);
    o4[0] = make_float4(acc[0],  acc[1],  acc[2],  acc[3]);
    o4[1] = make_float4(acc[4],  acc[5],  acc[6],  acc[7]);
    o4[2] = make_float4(acc[8],  acc[9],  acc[10], acc[11]);
    o4[3] = make_float4(acc[12], acc[13], acc[14], acc[15]);
}

// ---------------- fallback: atomic-scatter version ----------------
__global__ __launch_bounds__(256) void edge_kernel(
    const float* __restrict__ edge_attr, const int* __restrict__ ei,
    const int* __restrict__ ej, const unsigned short* __restrict__ Y,
    float* __restrict__ out) {
    const int e = blockIdx.x * 256 + threadIdx.x;
    if (e >= N_EDGES) return;
    const int di = ei[e];
    const int sj = ej[e];
    const float2 ea = ((const float2*)edge_attr)[e];
    if (di == sj) return;

    float ux = fminf(fmaxf(ea.x, -1.f), 1.f);
    float uy = fminf(fmaxf(ea.y, -1.f), 1.f);
    float tx = (ux + 1.f) * 1.5f;
    float ty = (uy + 1.f) * 1.5f;
    int kx0 = min((int)tx, 2);
    int ky0 = min((int)ty, 2);
    float fx = tx - (float)kx0;
    float fy = ty - (float)ky0;
    const float S = 1.f / 128.f;
    float w00 = (1.f - fx) * (1.f - fy) * S;
    float w01 = (1.f - fx) * fy * S;
    float w10 = fx * (1.f - fy) * S;
    float w11 = fx * fy * S;

    const unsigned short* base = Y + (size_t)sj * 256 + (kx0 * 4 + ky0) * 16;
    const uint4* pA = (const uint4*)base;
    const uint4* pB = (const uint4*)(base + 64);
    uint4 a0 = pA[0], a1 = pA[1], a2 = pA[2], a3 = pA[3];
    uint4 b0 = pB[0], b1 = pB[1], b2 = pB[2], b3 = pB[3];

    unsigned ra0[8] = {a0.x,a0.y,a0.z,a0.w, a1.x,a1.y,a1.z,a1.w};
    unsigned ra1[8] = {a2.x,a2.y,a2.z,a2.w, a3.x,a3.y,a3.z,a3.w};
    unsigned rb0[8] = {b0.x,b0.y,b0.z,b0.w, b1.x,b1.y,b1.z,b1.w};
    unsigned rb1[8] = {b2.x,b2.y,b2.z,b2.w, b3.x,b3.y,b3.z,b3.w};

    float* o16 = out + (size_t)di * 16;
#pragma unroll
    for (int q = 0; q < 8; ++q) {
        float m0 = bflo(ra0[q]) * w00 + bflo(ra1[q]) * w01
                 + bflo(rb0[q]) * w10 + bflo(rb1[q]) * w11;
        float m1 = bfhi(ra0[q]) * w00 + bfhi(ra1[q]) * w01
                 + bfhi(rb0[q]) * w10 + bfhi(rb1[q]) * w11;
        atomicAdd(o16 + 2 * q, m0);
        atomicAdd(o16 + 2 * q + 1, m1);
    }
}

// last-resort fallback: per-edge direct compute
__global__ __launch_bounds__(256) void edge_direct(
    const float* __restrict__ x, const float* __restrict__ edge_attr,
    const float* __restrict__ W, const int* __restrict__ ei,
    const int* __restrict__ ej, float* __restrict__ out) {
    const int e = blockIdx.x * 256 + threadIdx.x;
    if (e >= N_EDGES) return;
    const int di = ei[e];
    const int sj = ej[e];
    const float2 ea = ((const float2*)edge_attr)[e];
    if (di == sj) return;

    float ux = fminf(fmaxf(ea.x, -1.f), 1.f);
    float uy = fminf(fmaxf(ea.y, -1.f), 1.f);
    float tx = (ux + 1.f) * 1.5f, ty = (uy + 1.f) * 1.5f;
    int kx0 = min((int)tx, 2), ky0 = min((int)ty, 2);
    float fx = tx - (float)kx0, fy = ty - (float)ky0;
    const float S = 1.f / 128.f;
    float wgt[4] = {(1.f-fx)*(1.f-fy)*S, (1.f-fx)*fy*S, fx*(1.f-fy)*S, fx*fy*S};
    int kidx[4] = {kx0*4+ky0, kx0*4+ky0+1, (kx0+1)*4+ky0, (kx0+1)*4+ky0+1};

    const float* xj = x + (size_t)sj * 16;
    float xr[16];
#pragma unroll
    for (int i = 0; i < 16; ++i) xr[i] = xj[i];

    float msg[16];
#pragma unroll
    for (int o = 0; o < 16; ++o) msg[o] = 0.f;
#pragma unroll
    for (int p = 0; p < 4; ++p) {
        const float* wk = W + kidx[p] * 256;
#pragma unroll
        for (int i = 0; i < 16; ++i) {
            float xw = xr[i] * wgt[p];
#pragma unroll
            for (int o = 0; o < 16; ++o)
                msg[o] = fmaf(xw, wk[i * 16 + o], msg[o]);
        }
    }
    float* o16 = out + (size_t)di * 16;
#pragma unroll
    for (int o = 0; o < 16; ++o) atomicAdd(o16 + o, msg[o]);
}

extern "C" void kernel_launch(void* const* d_in, const int* in_sizes, int n_in,
                              void* d_out, int out_size, void* d_ws, size_t ws_size,
                              hipStream_t stream) {
    const float* x         = (const float*)d_in[0];
    const float* edge_attr = (const float*)d_in[1];
    const float* W         = (const float*)d_in[2];
    const int*   ei        = (const int*)d_in[3];
    const int*   ej        = (const int*)d_in[4];
    float* out = (float*)d_out;

    // workspace layout (all 16B aligned)
    const size_t oY     = 0;                               // 51,200,000 B
    const size_t oCnt   = oY + (size_t)N_NODES * 256 * 2;  // 400,000 B
    const size_t oOffs  = oCnt + 400000;                   // 400,016 B (N+1 ints, padded)
    const size_t oRank  = oOffs + 400016;                  // 3,200,000 B
    const size_t oMetaM = oRank + (size_t)N_EDGES * 4;     // 3,200,000 B
    const size_t oMetaW = oMetaM + (size_t)N_EDGES * 4;    // 12,800,000 B
    const size_t oBsum  = oMetaW + (size_t)N_EDGES * 16;   // 512 B
    const size_t oBexcl = oBsum + 512;                     // 512 B
    const size_t total  = oBexcl + 512;

    char* ws = (char*)d_ws;
    const size_t yBytes = (size_t)N_NODES * 256 * 2;

    if (ws_size >= total) {
        unsigned short* Y  = (unsigned short*)(ws + oY);
        int*    cnt   = (int*)(ws + oCnt);
        int*    offs  = (int*)(ws + oOffs);
        int*    rank  = (int*)(ws + oRank);
        int*    metaM = (int*)(ws + oMetaM);
        float4* metaW = (float4*)(ws + oMetaW);
        int*    bsum  = (int*)(ws + oBsum);
        int*    bexcl = (int*)(ws + oBexcl);

        hipMemsetAsync(cnt, 0, (size_t)N_NODES * 4, stream);
        dim3 gA((N_NODES + 255) / 256, 4);
        y_kernel<<<gA, 256, 0, stream>>>(x, W, Y);
        hist_kernel<<<(N_EDGES + 255) / 256, 256, 0, stream>>>(ei, ej, cnt, rank);
        scan1_kernel<<<SCAN_G, SCAN_B, 0, stream>>>(cnt, offs, bsum);
        scan2_kernel<<<1, 128, 0, stream>>>(bsum, bexcl, offs);
        scan3_kernel<<<SCAN_G, SCAN_B, 0, stream>>>(offs, bexcl);
        scatter_kernel<<<(N_EDGES + 255) / 256, 256, 0, stream>>>(
            edge_attr, ei, ej, offs, rank, metaM, metaW);
        gather_kernel<<<(N_NODES + 255) / 256, 256, 0, stream>>>(
            offs, metaM, metaW, Y, out);
    } else if (ws_size >= yBytes) {
        hipMemsetAsync(d_out, 0, (size_t)out_size * sizeof(float), stream);
        unsigned short* Y = (unsigned short*)d_ws;
        dim3 gA((N_NODES + 255) / 256, 4);
        y_kernel<<<gA, 256, 0, stream>>>(x, W, Y);
        edge_kernel<<<(N_EDGES + 255) / 256, 256, 0, stream>>>(edge_attr, ei, ej, Y, out);
    } else {
        hipMemsetAsync(d_out, 0, (size_t)out_size * sizeof(float), stream);
        edge_direct<<<(N_EDGES + 255) / 256, 256, 0, stream>>>(x, edge_attr, W, ei, ej, out);
    }
}